// Round 1
// baseline (77.024 us; speedup 1.0000x reference)
//
#include <hip/hip_runtime.h>
#include <hip/hip_bf16.h>

typedef __bf16 bf8 __attribute__((ext_vector_type(8)));
typedef unsigned short u16x8 __attribute__((ext_vector_type(8)));
typedef unsigned short u16x4 __attribute__((ext_vector_type(4)));
typedef float f32x4 __attribute__((ext_vector_type(4)));

union FragU { u16x8 u; bf8 b; };

static __device__ __forceinline__ unsigned short bfc(float f) {
  union { float ff; unsigned u; } v; v.ff = f;
  unsigned r = v.u + 0x7FFFu + ((v.u >> 16) & 1u);
  return (unsigned short)(r >> 16);
}

static __device__ __forceinline__ f32x4 MM(const FragU& a, const FragU& b, f32x4 c) {
  return __builtin_amdgcn_mfma_f32_16x16x32_bf16(a.b, b.b, c, 0, 0, 0);
}

#define NBATCH 524288
#define NTIL (NBATCH / 64)

// ---- LDS layout (ushort units) ----
// x tile: [64 samples][40], stride 80B -> b128 reads conflict-free (20 dwords/row)
#define XT 0
#define XS 40
// per-wave private region
#define PWBASE 2560
#define PWS 6784
#define HOFF 0      // h:   [16][72] feats 0..63 valid, 64..71 zero
#define HS 72
#define FEOFF 1152  // fea: [16][72] feats 0..41, const1 at 42, zeros up
#define TOFF 2304   // t:   [16][40] feats 0..19, const1 at 20
#define P1OFF 2944
#define P2OFF 3584
#define C1E0OFF 4224
#define C1E1OFF 4864
#define C2E0OFF 5504
#define C2E1OFF 6144
#define MS 40

__global__ __launch_bounds__(256, 2) void cdann_fwd(
    const float* __restrict__ gx, const int* __restrict__ gy,
    const float* __restrict__ gWf1, const float* __restrict__ gbf1,
    const float* __restrict__ gWf2, const float* __restrict__ gbf2,
    const float* __restrict__ gWt1, const float* __restrict__ gbt1,
    const float* __restrict__ gWt2, const float* __restrict__ gbt2,
    const float* __restrict__ gWp1, const float* __restrict__ gbp1,
    const float* __restrict__ gWp2, const float* __restrict__ gbp2,
    const float* __restrict__ gWp3, const float* __restrict__ gbp3,
    const float* __restrict__ gWc1, const float* __restrict__ gbc1,
    const float* __restrict__ gWc2, const float* __restrict__ gbc2,
    const float* __restrict__ gWc3, const float* __restrict__ gbc3,
    float* __restrict__ gout)
{
  __shared__ __align__(16) unsigned short lds[29696];
  const int tid = (int)threadIdx.x;
  const int lane = tid & 63;
  const int w = tid >> 6;
  const int g = lane >> 4;
  const int c15 = lane & 15;
  unsigned short* pw = lds + PWBASE + w * PWS;

  // ---- init per-wave LDS region: zeros + folded-bias const-1 slots ----
  for (int i = lane; i < PWS; i += 64) pw[i] = 0;
  if (lane < 16) {
    pw[TOFF    + lane*MS + 20] = 0x3F80;
    pw[P1OFF   + lane*MS + 20] = 0x3F80;
    pw[P2OFF   + lane*MS + 20] = 0x3F80;
    pw[C1E0OFF + lane*MS + 20] = 0x3F80;
    pw[C1E1OFF + lane*MS + 20] = 0x3F80;
    pw[C2E0OFF + lane*MS + 20] = 0x3F80;
    pw[C2E1OFF + lane*MS + 20] = 0x3F80;
  }

  // ---- build weight fragments: A-operand = W^T, lane: row n=(l&15), k=(l>>4)*8+j ----
  auto mk = [&](int ks, int nt, auto&& src) {
    FragU f;
    const int kb = ks*32 + g*8;
    const int n = nt*16 + c15;
#pragma unroll
    for (int j = 0; j < 8; ++j) f.u[j] = bfc(src(kb + j, n));
    return f;
  };
  auto s_f1 = [&](int k, int n) -> float {           // K=32 (30 + const1), N=64
    if (k < 30) return gWf1[k*64 + n];
    if (k == 30) return gbf1[n];
    return 0.f;
  };
  auto s_f2 = [&](int k, int n) -> float {           // K=64, N=48 (42 valid)
    return (n < 42) ? gWf2[k*42 + n] : 0.f;
  };
  auto s_tp = [&](int k, int n) -> float {           // packed [t1 | p1], const1 at k=42
    if (n < 20) { if (k < 42) return gWt1[k*20 + n]; if (k == 42) return gbt1[n]; return 0.f; }
    if (n < 40) { int m = n - 20; if (k < 42) return gWp1[k*20 + m]; if (k == 42) return gbp1[m]; return 0.f; }
    return 0.f;
  };
  auto s_c1 = [&](int k, int n) -> float {           // packed [c1e0 | c1e1]
    if (n >= 40) return 0.f;
    int e = (n >= 20) ? 1 : 0; int m = n - 20*e;
    if (k < 42) return gWc1[(e*42 + k)*20 + m];
    if (k == 42) return gbc1[e*20 + m];
    return 0.f;
  };
  auto s_t2 = [&](int k, int n) -> float {
    if (n >= 2) return 0.f;
    if (k < 20) return gWt2[k*2 + n];
    if (k == 20) return gbt2[n];
    return 0.f;
  };
  auto s_p2 = [&](int k, int n) -> float {
    if (n >= 20) return 0.f;
    if (k < 20) return gWp2[k*20 + n];
    if (k == 20) return gbp2[n];
    return 0.f;
  };
  auto s_p3 = [&](int k, int n) -> float {
    if (n >= 6) return 0.f;
    if (k < 20) return gWp3[k*6 + n];
    if (k == 20) return gbp3[n];
    return 0.f;
  };
  auto s_c2 = [&](int e, int k, int n) -> float {
    if (n >= 20) return 0.f;
    if (k < 20) return gWc2[(e*20 + k)*20 + n];
    if (k == 20) return gbc2[e*20 + n];
    return 0.f;
  };
  auto s_c3 = [&](int e, int k, int n) -> float {
    if (n >= 6) return 0.f;
    if (k < 20) return gWc3[(e*20 + k)*6 + n];
    if (k == 20) return gbc3[e*6 + n];
    return 0.f;
  };

  FragU wF1[4], wF2[2][3], wTP[2][3], wC1[2][3];
  FragU wT2, wP2[2], wP3, wC2a[2], wC2b[2], wC3a, wC3b;
#pragma unroll
  for (int nt = 0; nt < 4; ++nt) wF1[nt] = mk(0, nt, s_f1);
#pragma unroll
  for (int ks = 0; ks < 2; ++ks)
#pragma unroll
    for (int nt = 0; nt < 3; ++nt) {
      wF2[ks][nt] = mk(ks, nt, s_f2);
      wTP[ks][nt] = mk(ks, nt, s_tp);
      wC1[ks][nt] = mk(ks, nt, s_c1);
    }
  wT2 = mk(0, 0, s_t2);
#pragma unroll
  for (int nt = 0; nt < 2; ++nt) {
    wP2[nt]  = mk(0, nt, s_p2);
    wC2a[nt] = mk(0, nt, [&](int k, int n){ return s_c2(0, k, n); });
    wC2b[nt] = mk(0, nt, [&](int k, int n){ return s_c2(1, k, n); });
  }
  wP3  = mk(0, 0, s_p3);
  wC3a = mk(0, 0, [&](int k, int n){ return s_c3(0, k, n); });
  wC3b = mk(0, 0, [&](int k, int n){ return s_c3(1, k, n); });

  // f2 bias can't be folded (K=64 full): 12 per-lane regs
  float biasF2[3][4];
#pragma unroll
  for (int nt = 0; nt < 3; ++nt)
#pragma unroll
    for (int r = 0; r < 4; ++r) {
      int n = nt*16 + g*4 + r;
      biasF2[nt][r] = (n < 42) ? gbf2[n] : 0.f;
    }

  const f32x4 zf = {0.f, 0.f, 0.f, 0.f};
  float* const outT = gout;
  float* const outP = gout + (size_t)2*NBATCH;
  float* const outC = gout + (size_t)8*NBATCH;

  for (int it = blockIdx.x; it < NTIL; it += gridDim.x) {
    const int sbase = it * 64;
    __syncthreads();
    // ---- stage x tile: 64 samples x 30 f32 -> bf16, +1.0 at 30, zeros 31..39 ----
    {
      const int s = tid >> 2, part = tid & 3;
      const float* xr = gx + (size_t)(sbase + s)*30 + part*8;
      u16x8 v;
      if (part < 3) {
#pragma unroll
        for (int j = 0; j < 8; ++j) v[j] = bfc(xr[j]);
      } else {
#pragma unroll
        for (int j = 0; j < 6; ++j) v[j] = bfc(xr[j]);
        v[6] = 0x3F80; v[7] = 0;
      }
      *(u16x8*)(lds + XT + s*XS + part*8) = v;
      if (part == 0) {
        u16x8 z = {0,0,0,0,0,0,0,0};
        *(u16x8*)(lds + XT + s*XS + 32) = z;
      }
    }
    __syncthreads();

    // ---- per-wave 16-sample chain (Y^T = W^T X^T per layer) ----
    // f1: x(K=32) -> h(N=64), bias folded
    FragU bx; bx.u = *(const u16x8*)(lds + XT + (w*16 + c15)*XS + g*8);
    f32x4 aH[4];
#pragma unroll
    for (int nt = 0; nt < 4; ++nt) aH[nt] = MM(wF1[nt], bx, zf);
#pragma unroll
    for (int nt = 0; nt < 4; ++nt) {
      u16x4 hv;
#pragma unroll
      for (int r = 0; r < 4; ++r) hv[r] = bfc(fmaxf(aH[nt][r], 0.f));
      *(u16x4*)(pw + HOFF + c15*HS + nt*16 + g*4) = hv;
    }

    // f2: h(K=64) -> fea(N=48, 42 valid), reg bias
    FragU bh0, bh1;
    bh0.u = *(const u16x8*)(pw + HOFF + c15*HS + g*8);
    bh1.u = *(const u16x8*)(pw + HOFF + c15*HS + 32 + g*8);
#pragma unroll
    for (int nt = 0; nt < 3; ++nt) {
      f32x4 a = MM(wF2[0][nt], bh0, zf);
      a = MM(wF2[1][nt], bh1, a);
      u16x4 fv;
#pragma unroll
      for (int r = 0; r < 4; ++r) fv[r] = bfc(fmaxf(a[r] + biasF2[nt][r], 0.f));
      *(u16x4*)(pw + FEOFF + c15*HS + nt*16 + g*4) = fv;
    }
    if (lane < 16) pw[FEOFF + lane*HS + 42] = 0x3F80;  // rewrite const-1 (f2 wrote 0 there)

    FragU bfe0, bfe1;
    bfe0.u = *(const u16x8*)(pw + FEOFF + c15*HS + g*8);
    bfe1.u = *(const u16x8*)(pw + FEOFF + c15*HS + 32 + g*8);

    // packed t1|p1 (K=64 over fea, const1 at 42)
#pragma unroll
    for (int nt = 0; nt < 3; ++nt) {
      f32x4 a = MM(wTP[0][nt], bfe0, zf);
      a = MM(wTP[1][nt], bfe1, a);
      const int q = nt*16 + g*4;
      u16x4 vv;
#pragma unroll
      for (int r = 0; r < 4; ++r) vv[r] = bfc(fmaxf(a[r], 0.f));
      if (q < 20)      *(u16x4*)(pw + TOFF  + c15*MS + q) = vv;
      else if (q < 40) *(u16x4*)(pw + P1OFF + c15*MS + (q - 20)) = vv;
    }
    // packed c1e0|c1e1
#pragma unroll
    for (int nt = 0; nt < 3; ++nt) {
      f32x4 a = MM(wC1[0][nt], bfe0, zf);
      a = MM(wC1[1][nt], bfe1, a);
      const int q = nt*16 + g*4;
      u16x4 vv;
#pragma unroll
      for (int r = 0; r < 4; ++r) vv[r] = bfc(fmaxf(a[r], 0.f));
      if (q < 20)      *(u16x4*)(pw + C1E0OFF + c15*MS + q) = vv;
      else if (q < 40) *(u16x4*)(pw + C1E1OFF + c15*MS + (q - 20)) = vv;
    }

    // t2: t(K=32, const1 at 20) -> task (n=0,1)
    FragU btf; btf.u = *(const u16x8*)(pw + TOFF + c15*MS + g*8);
    f32x4 at = MM(wT2, btf, zf);

    // p2 -> p2 tile (relu)
    FragU bp1f; bp1f.u = *(const u16x8*)(pw + P1OFF + c15*MS + g*8);
#pragma unroll
    for (int nt = 0; nt < 2; ++nt) {
      f32x4 a = MM(wP2[nt], bp1f, zf);
      const int q = nt*16 + g*4;
      u16x4 vv;
#pragma unroll
      for (int r = 0; r < 4; ++r) vv[r] = bfc(fmaxf(a[r], 0.f));
      if (q < 20) *(u16x4*)(pw + P2OFF + c15*MS + q) = vv;
    }
    // p3 -> pd (n=0..5)
    FragU bp2f; bp2f.u = *(const u16x8*)(pw + P2OFF + c15*MS + g*8);
    f32x4 ap = MM(wP3, bp2f, zf);

    // c2 experts
    FragU bc1e0; bc1e0.u = *(const u16x8*)(pw + C1E0OFF + c15*MS + g*8);
#pragma unroll
    for (int nt = 0; nt < 2; ++nt) {
      f32x4 a = MM(wC2a[nt], bc1e0, zf);
      const int q = nt*16 + g*4;
      u16x4 vv;
#pragma unroll
      for (int r = 0; r < 4; ++r) vv[r] = bfc(fmaxf(a[r], 0.f));
      if (q < 20) *(u16x4*)(pw + C2E0OFF + c15*MS + q) = vv;
    }
    FragU bc1e1; bc1e1.u = *(const u16x8*)(pw + C1E1OFF + c15*MS + g*8);
#pragma unroll
    for (int nt = 0; nt < 2; ++nt) {
      f32x4 a = MM(wC2b[nt], bc1e1, zf);
      const int q = nt*16 + g*4;
      u16x4 vv;
#pragma unroll
      for (int r = 0; r < 4; ++r) vv[r] = bfc(fmaxf(a[r], 0.f));
      if (q < 20) *(u16x4*)(pw + C2E1OFF + c15*MS + q) = vv;
    }

    // c3 experts -> cd0/cd1 (n=0..5)
    FragU bc2e0; bc2e0.u = *(const u16x8*)(pw + C2E0OFF + c15*MS + g*8);
    f32x4 cd0 = MM(wC3a, bc2e0, zf);
    FragU bc2e1; bc2e1.u = *(const u16x8*)(pw + C2E1OFF + c15*MS + g*8);
    f32x4 cd1 = MM(wC3b, bc2e1, zf);

    // ---- outputs: C-frag lane (g,r) holds row n=g*4+r, col sample=c15 ----
    const int sg = sbase + w*16 + c15;
    const int ys = gy[sg];
    f32x4 cd;
#pragma unroll
    for (int r = 0; r < 4; ++r) cd[r] = ys ? cd1[r] : cd0[r];

    if (g == 0) {
      float* ot = outT + (size_t)sg*2;
      ot[0] = at[0]; ot[1] = at[1];
      float* op = outP + (size_t)sg*6;
      op[0] = ap[0]; op[1] = ap[1]; op[2] = ap[2]; op[3] = ap[3];
      float* oc = outC + (size_t)sg*6;
      oc[0] = cd[0]; oc[1] = cd[1]; oc[2] = cd[2]; oc[3] = cd[3];
    } else if (g == 1) {
      float* op = outP + (size_t)sg*6;
      op[4] = ap[0]; op[5] = ap[1];
      float* oc = outC + (size_t)sg*6;
      oc[4] = cd[0]; oc[5] = cd[1];
    }
  }
}

extern "C" void kernel_launch(void* const* d_in, const int* in_sizes, int n_in,
                              void* d_out, int out_size, void* d_ws, size_t ws_size,
                              hipStream_t stream) {
  (void)in_sizes; (void)n_in; (void)d_ws; (void)ws_size; (void)out_size;
  const float* gx  = (const float*)d_in[0];
  const int*   gy  = (const int*)d_in[1];
  const float* Wf1 = (const float*)d_in[2];  const float* bf1 = (const float*)d_in[3];
  const float* Wf2 = (const float*)d_in[4];  const float* bf2 = (const float*)d_in[5];
  const float* Wt1 = (const float*)d_in[6];  const float* bt1 = (const float*)d_in[7];
  const float* Wt2 = (const float*)d_in[8];  const float* bt2 = (const float*)d_in[9];
  const float* Wp1 = (const float*)d_in[10]; const float* bp1 = (const float*)d_in[11];
  const float* Wp2 = (const float*)d_in[12]; const float* bp2 = (const float*)d_in[13];
  const float* Wp3 = (const float*)d_in[14]; const float* bp3 = (const float*)d_in[15];
  const float* Wc1 = (const float*)d_in[16]; const float* bc1 = (const float*)d_in[17];
  const float* Wc2 = (const float*)d_in[18]; const float* bc2 = (const float*)d_in[19];
  const float* Wc3 = (const float*)d_in[20]; const float* bc3 = (const float*)d_in[21];
  float* out = (float*)d_out;

  cdann_fwd<<<dim3(512), dim3(256), 0, stream>>>(
      gx, gy, Wf1, bf1, Wf2, bf2, Wt1, bt1, Wt2, bt2,
      Wp1, bp1, Wp2, bp2, Wp3, bp3, Wc1, bc1, Wc2, bc2, Wc3, bc3, out);
}